// Round 1
// baseline (732.781 us; speedup 1.0000x reference)
//
#include <hip/hip_runtime.h>

// 4-layer 5-point cross-stencil CNN, implicit GEMM on MFMA (MI355X gfx950).
// Round 6: persistent-CU gmid rewrite.
//   Old gmid was latency/traffic-bound: per-k-step B-fragment loads from L2
//   (1.3 GB weight re-reads per dispatch), 16 MFMA of cover per load batch,
//   3 waves/SIMD. New gmid:
//    - 256 blocks (1 per CU), 512 threads (8 waves), persistent over the 16
//      j-tiles of an 8-row band. Wave = 4 rows x 32 oc.
//    - All 40 B-fragments (tap-major, K16 steps) resident in 160 VGPRs,
//      loaded once: k-loop is ds_read + MFMA only.
//    - 32x32x16 MFMA: A[m=lane&31][k=(lane>>5)*8+j], B symmetric,
//      D: col(lane&31)=oc, row=(reg&3)+8*(reg>>2)+4*(lane>>5) = m.
//      m maps to (rowsel=m>>4, px=m&15). Stores are 64B-contiguous in oc.
//    - Input tile [10 rows][18 px][128 ic] fp16, double-buffered in LDS,
//      staged with global_load_lds(16B) issued at tile start (in flight
//      across whole k-loop). 16B chunks XOR-swizzled by site&7 via
//      pre-swizzled per-lane SOURCE address (linear LDS dest), reads apply
//      the same XOR -> ~2-way banks instead of 16-way.
//    - Halo: clamped source addresses + zero-fixup pass on edge tiles only.

#define BB   8
#define HH   256
#define WW   256

typedef _Float16 f16x8  __attribute__((ext_vector_type(8)));
typedef float    f32x4  __attribute__((ext_vector_type(4)));
typedef float    f32x16 __attribute__((ext_vector_type(16)));

// K-major fp16 weight tables (rewritten every launch by prep).
__device__ _Float16 W1g[128 * 32];       // [oc][k], k=tap*6+ic, 30..31 = 0
__device__ _Float16 W2g[20 * 128 * 32];  // [ks=tap*4+kc][oc][icb]
__device__ _Float16 W3g[20 * 128 * 32];
__device__ _Float16 W4g[5 * 16 * 128];   // [tap][oc(pad16)][ic]

__global__ void prep(const float* __restrict__ w1, const float* __restrict__ w2,
                     const float* __restrict__ w3, const float* __restrict__ w4)
{
    int idx = blockIdx.x * 256 + threadIdx.x;
    if (idx < 81920) {                                  // W2g
        int icb = idx & 31, oc = (idx >> 5) & 127, ks = idx >> 12;
        int tap = ks >> 2, ic = (ks & 3) * 32 + icb;
        W2g[idx] = (_Float16)w2[(oc * 128 + ic) * 5 + tap];
    } else if (idx < 163840) {                          // W3g
        int k = idx - 81920;
        int icb = k & 31, oc = (k >> 5) & 127, ks = k >> 12;
        int tap = ks >> 2, ic = (ks & 3) * 32 + icb;
        W3g[k] = (_Float16)w3[(oc * 128 + ic) * 5 + tap];
    } else if (idx < 174080) {                          // W4g
        int k = idx - 163840;
        int t = k / 2048, oc = (k >> 7) & 15, ic = k & 127;
        W4g[k] = (_Float16)((oc < 6) ? w4[(oc * 128 + ic) * 5 + t] : 0.f);
    } else if (idx < 178176) {                          // W1g
        int k = idx - 174080;
        int kk = k & 31, oc = k >> 5;
        float v = 0.f;
        if (kk < 30) {
            int tap = (kk * 43) >> 8;                   // kk/6 for kk<30
            int ic = kk - 6 * tap;
            v = w1[(oc * 6 + ic) * 5 + tap];
        }
        W1g[k] = (_Float16)v;
    }
}

// ---------------- L1: MFMA, K=32 (tap*6+ic, padded). NCHW fp32 -> NHWC fp16.
__global__ __launch_bounds__(256, 3) void g1(
    const float* __restrict__ x, const float* __restrict__ bias,
    _Float16* __restrict__ outp)
{
    __shared__ _Float16 Ap[128 * 40];
    const int tid = threadIdx.x;
    const int j0 = blockIdx.x * 16, i0 = blockIdx.y * 8, b = blockIdx.z;
    const int px = tid & 127, half = tid >> 7;
    const int pr = px >> 4, pp = px & 15;
#pragma unroll
    for (int it = 0; it < 16; ++it) {
        int k = it * 2 + half;
        float v = 0.f;
        if (k < 30) {
            int tap = (k * 43) >> 8, ic = k - 6 * tap;
            int di = (tap == 1) ? -1 : ((tap == 2) ? 1 : 0);
            int dj = (tap == 3) ? -1 : ((tap == 4) ? 1 : 0);
            int gi = i0 + pr + di, gj = j0 + pp + dj;
            if (((unsigned)gi < 256u) && ((unsigned)gj < 256u))
                v = x[(((size_t)b * 6 + ic) * 256 + gi) * 256 + gj];
        }
        Ap[px * 40 + k] = (_Float16)v;
    }
    __syncthreads();

    const int lane = tid & 63, w = tid >> 6, l16 = lane & 15, quad = lane >> 4;
    f32x4 acc[2][8] = {};
    f16x8 a0 = *(const f16x8*)&Ap[((2 * w + 0) * 16 + l16) * 40 + quad * 8];
    f16x8 a1 = *(const f16x8*)&Ap[((2 * w + 1) * 16 + l16) * 40 + quad * 8];
#pragma unroll
    for (int nf = 0; nf < 8; ++nf) {
        f16x8 bf = *(const f16x8*)&W1g[(nf * 16 + l16) * 32 + quad * 8];
        acc[0][nf] = __builtin_amdgcn_mfma_f32_16x16x32_f16(a0, bf, acc[0][nf], 0, 0, 0);
        acc[1][nf] = __builtin_amdgcn_mfma_f32_16x16x32_f16(a1, bf, acc[1][nf], 0, 0, 0);
    }
#pragma unroll
    for (int mf = 0; mf < 2; ++mf) {
        const size_t rowb = ((size_t)b * 256 + i0 + 2 * w + mf) * 256 + j0;
#pragma unroll
        for (int nf = 0; nf < 8; ++nf) {
            const float bv = bias[nf * 16 + l16];
#pragma unroll
            for (int r = 0; r < 4; ++r)
                outp[(rowb + quad * 4 + r) * 128 + nf * 16 + l16] =
                    (_Float16)fmaxf(acc[mf][nf][r] + bv, 0.f);
        }
    }
}

// ---------------- middle layers: persistent 1 block/CU, weights in VGPRs ----
// Block: 8-row band x (16 j-tiles of 16 px) x 128 oc. 512 thr = 8 waves:
// mg = wid&1 -> rows 4mg..4mg+3, ng = wid>>1 -> oc 32*ng..+31.
// LDS tile: 180 sites (10 rows x 18 px) x 128 ic halves, x2 buffers = 92160 B.
template<int LAYER>
__global__ __launch_bounds__(512, 2) void gmid(
    const _Float16* __restrict__ in, const float* __restrict__ bias,
    _Float16* __restrict__ outp)
{
    const _Float16* wt = (LAYER == 2) ? W2g : W3g;
    __shared__ __align__(16) _Float16 Albuf[2][180 * 128];

    const int tid  = threadIdx.x;
    const int lane = tid & 63, wid = tid >> 6;
    const int l32 = lane & 31, khalf = lane >> 5;
    const int rsel = (lane >> 4) & 1, pxl = lane & 15;
    const int mg = wid & 1, ng = wid >> 1;
    const int n0 = ng * 32;
    const int iband = blockIdx.x, b = blockIdx.y;
    const int i0 = iband * 8;
    const bool top = (iband == 0), bot = (iband == 31);

    // ---- staging precompute: 6 global_load_lds per wave, 45 total (=180 sites)
    // instr m stages sites 4m..4m+3 linearly; lane l -> site 4m+(l>>4),
    // stored chunk (l&15) holds SOURCE chunk (l&15)^(site&7)  (XOR swizzle).
    int sgbase[6], sp6[6], slds[6];
#pragma unroll
    for (int k = 0; k < 6; ++k) {
        const int m = wid + 8 * k;
        const int s = 4 * m + (lane >> 4);
        const int r = (s * 114) >> 11;                  // s/18 for s<288
        const int p = s - 18 * r;
        int gi = i0 - 1 + r; gi = gi < 0 ? 0 : (gi > 255 ? 255 : gi);
        sgbase[k] = ((b * 256 + gi) * 256) * 128 + ((pxl ^ (s & 7)) << 3);
        sp6[k] = p;
        slds[k] = m * 512;                              // halves (= m*1024 B)
    }

    auto stage = [&](int j0p, _Float16* bp) {
#pragma unroll
        for (int k = 0; k < 6; ++k) {
            if (wid + 8 * k < 45) {
                int gj = j0p - 1 + sp6[k];
                gj = gj < 0 ? 0 : (gj > 255 ? 255 : gj);
                const _Float16* src = in + sgbase[k] + gj * 128;
                __builtin_amdgcn_global_load_lds(
                    (const __attribute__((address_space(1))) void*)src,
                    (__attribute__((address_space(3))) void*)(bp + slds[k]),
                    16, 0, 0);
            }
        }
    };

    // zero the halo sites that were clamp-loaded from wrong rows/cols
    auto fixup = [&](_Float16* bp, bool left, bool right) {
        const int gidx = tid >> 3, c = tid & 7;
        int sid = -1;
        if (gidx < 18)      { if (top)   sid = gidx; }            // r=0 row
        else if (gidx < 36) { if (bot)   sid = 162 + gidx - 18; } // r=9 row
        else if (gidx < 46) { if (left)  sid = (gidx - 36) * 18; }        // p=0
        else if (gidx < 56) { if (right) sid = (gidx - 46) * 18 + 17; }   // p=17
        if (sid >= 0) {
            const f16x8 z = {};
            *(f16x8*)(bp + sid * 128 + c * 16)     = z;
            *(f16x8*)(bp + sid * 128 + c * 16 + 8) = z;
        }
    };

    // ---- resident weights: 40 K16-steps x 32 oc, 160 VGPR, loaded once ----
    f16x8 Bres[40];
    {
        const _Float16* wbase = wt + (size_t)(n0 + l32) * 32 + khalf * 8;
#pragma unroll
        for (int ks = 0; ks < 40; ++ks) {
            const int tap = ks >> 3, ksub = ks & 7;
            // ic = ksub*16 + khalf*8 + j  (matches A fragment k order)
            Bres[ks] = *(const f16x8*)(wbase + (tap * 4 + (ksub >> 1)) * 4096 +
                                       (ksub & 1) * 16);
        }
    }
    const float bv = bias[n0 + l32];

    // A fragment read: site = (DR[tap]+4mg+2f+rsel)*18 + DP[tap] + pxl
    constexpr int DS_[5] = {19, 1, 37, 18, 20};   // DR*18+DP: c,up,down,left,right
    const int s00 = (4 * mg + rsel) * 18 + pxl;
    auto lda = [&](const _Float16* bp, int ks, int f) -> f16x8 {
        const int tap = ks >> 3, ksub = ks & 7;
        const int s = s00 + f * 36 + DS_[tap];
        const int ch = ((ksub << 1) | khalf) ^ (s & 7);
        return *(const f16x8*)(bp + s * 128 + ch * 8);
    };

    // ---- prologue: stage tile 0 ----
    stage(0, Albuf[0]);
    __syncthreads();
    fixup(Albuf[0], true, false);
    __syncthreads();

#pragma unroll 1
    for (int jt = 0; jt < 16; ++jt) {
        _Float16* bcur = Albuf[jt & 1];
        _Float16* bnxt = Albuf[(jt + 1) & 1];
        if (jt < 15) stage((jt + 1) * 16, bnxt);   // async, spans whole k-loop

        f32x16 accA = {}, accB = {};
        f16x8 Af[3][2];
        Af[0][0] = lda(bcur, 0, 0); Af[0][1] = lda(bcur, 0, 1);
        Af[1][0] = lda(bcur, 1, 0); Af[1][1] = lda(bcur, 1, 1);
#pragma unroll
        for (int ks = 0; ks < 40; ++ks) {
            if (ks + 2 < 40) {
                Af[(ks + 2) % 3][0] = lda(bcur, ks + 2, 0);
                Af[(ks + 2) % 3][1] = lda(bcur, ks + 2, 1);
            }
            accA = __builtin_amdgcn_mfma_f32_32x32x16_f16(Af[ks % 3][0], Bres[ks], accA, 0, 0, 0);
            accB = __builtin_amdgcn_mfma_f32_32x32x16_f16(Af[ks % 3][1], Bres[ks], accB, 0, 0, 0);
        }

        // epilogue: D col(lane&31)=oc, m=(r&3)+8*(r>>2)+4*khalf -> row/px
        const int j0 = jt * 16;
#pragma unroll
        for (int f = 0; f < 2; ++f) {
            const f32x16 a = f ? accB : accA;
#pragma unroll
            for (int r = 0; r < 16; ++r) {
                const int row = i0 + 4 * mg + 2 * f + (r >> 3);
                const int pj  = j0 + (r & 3) + 4 * khalf + 8 * ((r >> 2) & 1);
                outp[((size_t)(b * 256 + row) * 256 + pj) * 128 + n0 + l32] =
                    (_Float16)fmaxf(a[r] + bv, 0.f);
            }
        }

        if (jt < 15) {
            __syncthreads();                       // staging of bnxt landed
            const bool right = (jt + 1 == 15);
            if (top | bot | right) {
                fixup(bnxt, false, right);
                __syncthreads();
            }
        }
    }
}

// ---------------- L4: 128 -> 6 (pad 16), MFMA, fp32 NCHW out ----------------
__global__ __launch_bounds__(256, 3) void g4(
    const _Float16* __restrict__ in, const float* __restrict__ bias,
    float* __restrict__ outp)
{
    __shared__ _Float16 Al[6 * 18 * 136];
    const int tid = threadIdx.x;
    const int jt = blockIdx.x, it = blockIdx.y, b = blockIdx.z;
    const int i0 = it * 4, j0 = jt * 16;

    for (int t = tid; t < 6 * 18 * 16; t += 256) {
        int r = t / 288, rem = t % 288, p = rem >> 4, q = rem & 15;
        int gi = i0 - 1 + r, gj = j0 - 1 + p;
        f16x8 v = {0, 0, 0, 0, 0, 0, 0, 0};
        if (((unsigned)gi < 256u) && ((unsigned)gj < 256u))
            v = *(const f16x8*)&in[(((size_t)b * 256 + gi) * 256 + gj) * 128 + q * 8];
        *(f16x8*)&Al[(r * 18 + p) * 136 + q * 8] = v;
    }
    __syncthreads();

    const int lane = tid & 63, wid = tid >> 6;
    const int l16 = lane & 15, quad = lane >> 4;
    f32x4 acc = {};
    const int DR[5] = {1, 0, 2, 1, 1}, DP[5] = {1, 1, 1, 0, 2};

#pragma unroll
    for (int ks = 0; ks < 20; ++ks) {
        const int tap = ks >> 2, kc = ks & 3;
        const int koff = kc * 32 + quad * 8;
        f16x8 bf = *(const f16x8*)&W4g[(size_t)(tap * 16 + l16) * 128 + koff];
        f16x8 af = *(const f16x8*)&Al[((DR[tap] + wid) * 18 + DP[tap] + l16) * 136 + koff];
        acc = __builtin_amdgcn_mfma_f32_16x16x32_f16(af, bf, acc, 0, 0, 0);
    }

    if (l16 < 6) {
        const float bb = bias[l16];
        const int i = i0 + wid;
#pragma unroll
        for (int vi = 0; vi < 4; ++vi) {
            int jj = j0 + quad * 4 + vi;
            outp[(((size_t)b * 6 + l16) << 16) + i * 256 + jj] = acc[vi] + bb;
        }
    }
}

extern "C" void kernel_launch(void* const* d_in, const int* in_sizes, int n_in,
                              void* d_out, int out_size, void* d_ws, size_t ws_size,
                              hipStream_t stream) {
    const float* x  = (const float*)d_in[0];
    const float* w1 = (const float*)d_in[1];
    const float* b1 = (const float*)d_in[2];
    const float* w2 = (const float*)d_in[3];
    const float* b2 = (const float*)d_in[4];
    const float* w3 = (const float*)d_in[5];
    const float* b3 = (const float*)d_in[6];
    const float* w4 = (const float*)d_in[7];
    const float* b4 = (const float*)d_in[8];
    float* out = (float*)d_out;

    const size_t act = (size_t)BB * HH * WW * 128;
    _Float16* A1 = (_Float16*)d_ws;
    _Float16* A2 = A1 + act;                    // exactly 268435456 B total

    prep<<<696, 256, 0, stream>>>(w1, w2, w3, w4);
    dim3 blk(256, 1, 1);
    dim3 gm(16, 32, 8);                         // 16-px x 8-row tiles
    g1<<<gm, blk, 0, stream>>>(x, b1, A1);
    gmid<2><<<dim3(32, 8, 1), dim3(512, 1, 1), 0, stream>>>(A1, b2, A2);
    gmid<3><<<dim3(32, 8, 1), dim3(512, 1, 1), 0, stream>>>(A2, b3, A1);
    g4<<<dim3(16, 64, 8), blk, 0, stream>>>(A1, b4, out);
}

// Round 2
// 606.503 us; speedup vs baseline: 1.2082x; 1.2082x over previous
//
#include <hip/hip_runtime.h>

// 4-layer 5-point cross-stencil CNN, implicit GEMM on MFMA (MI355X gfx950).
// Round 7: revert to round-5 structure (proven 178us/gmid), deepen B prefetch.
//   Round-6 post-mortem: resident-weight rewrite spilled (VGPR cap 128 vs 160
//   needed) and its 2-MFMA k-step had no latency cover -> 263us. Reverted.
//   This round: gmid k-loop uses ring-3 B prefetch (global/L2 weights loaded
//   2 iterations = ~160 MFMA-cycles ahead) + ring-2 A (LDS, 1 iter ahead).
//   Before the MFMAs of step ks there are 8 newer B-loads outstanding ->
//   compiler emits counted vmcnt(8), never drains (AITER pattern).
//   +16 VGPR vs round-5 (~164/wave incl acc) stays under the 170 cap of
//   3 waves/SIMD (__launch_bounds__(256,3)) -> occupancy unchanged.
// MFMA 16x16x32_f16 layouts (verified round 3):
//   A[m=lane&15][k=quad*8+j], B[n=lane&15][k=quad*8+j], C: col=lane&15,
//   row=quad*4+reg.   Taps: 0=c,1=up,2=down,3=left,4=right.

#define BB   8
#define HH   256
#define WW   256

typedef _Float16 f16x8 __attribute__((ext_vector_type(8)));
typedef float    f32x4 __attribute__((ext_vector_type(4)));

// K-major fp16 weight tables (rewritten every launch by prep).
__device__ _Float16 W1g[128 * 32];       // [oc][k], k=tap*6+ic, 30..31 = 0
__device__ _Float16 W2g[20 * 128 * 32];  // [ks=tap*4+kc][oc][icb]
__device__ _Float16 W3g[20 * 128 * 32];
__device__ _Float16 W4g[5 * 16 * 128];   // [tap][oc(pad16)][ic]

__global__ void prep(const float* __restrict__ w1, const float* __restrict__ w2,
                     const float* __restrict__ w3, const float* __restrict__ w4)
{
    int idx = blockIdx.x * 256 + threadIdx.x;
    if (idx < 81920) {                                  // W2g
        int icb = idx & 31, oc = (idx >> 5) & 127, ks = idx >> 12;
        int tap = ks >> 2, ic = (ks & 3) * 32 + icb;
        W2g[idx] = (_Float16)w2[(oc * 128 + ic) * 5 + tap];
    } else if (idx < 163840) {                          // W3g
        int k = idx - 81920;
        int icb = k & 31, oc = (k >> 5) & 127, ks = k >> 12;
        int tap = ks >> 2, ic = (ks & 3) * 32 + icb;
        W3g[k] = (_Float16)w3[(oc * 128 + ic) * 5 + tap];
    } else if (idx < 174080) {                          // W4g
        int k = idx - 163840;
        int t = k / 2048, oc = (k >> 7) & 15, ic = k & 127;
        W4g[k] = (_Float16)((oc < 6) ? w4[(oc * 128 + ic) * 5 + t] : 0.f);
    } else if (idx < 178176) {                          // W1g
        int k = idx - 174080;
        int kk = k & 31, oc = k >> 5;
        float v = 0.f;
        if (kk < 30) {
            int tap = (kk * 43) >> 8;                   // kk/6 for kk<30
            int ic = kk - 6 * tap;
            v = w1[(oc * 6 + ic) * 5 + tap];
        }
        W1g[k] = (_Float16)v;
    }
}

// ---------------- L1: MFMA, K=32 (tap*6+ic, padded). NCHW fp32 -> NHWC fp16.
__global__ __launch_bounds__(256, 3) void g1(
    const float* __restrict__ x, const float* __restrict__ bias,
    _Float16* __restrict__ outp)
{
    __shared__ _Float16 Ap[128 * 40];
    const int tid = threadIdx.x;
    const int j0 = blockIdx.x * 16, i0 = blockIdx.y * 8, b = blockIdx.z;
    const int px = tid & 127, half = tid >> 7;
    const int pr = px >> 4, pp = px & 15;
#pragma unroll
    for (int it = 0; it < 16; ++it) {
        int k = it * 2 + half;
        float v = 0.f;
        if (k < 30) {
            int tap = (k * 43) >> 8, ic = k - 6 * tap;
            int di = (tap == 1) ? -1 : ((tap == 2) ? 1 : 0);
            int dj = (tap == 3) ? -1 : ((tap == 4) ? 1 : 0);
            int gi = i0 + pr + di, gj = j0 + pp + dj;
            if (((unsigned)gi < 256u) && ((unsigned)gj < 256u))
                v = x[(((size_t)b * 6 + ic) * 256 + gi) * 256 + gj];
        }
        Ap[px * 40 + k] = (_Float16)v;
    }
    __syncthreads();

    const int lane = tid & 63, w = tid >> 6, l16 = lane & 15, quad = lane >> 4;
    f32x4 acc[2][8] = {};
    f16x8 a0 = *(const f16x8*)&Ap[((2 * w + 0) * 16 + l16) * 40 + quad * 8];
    f16x8 a1 = *(const f16x8*)&Ap[((2 * w + 1) * 16 + l16) * 40 + quad * 8];
#pragma unroll
    for (int nf = 0; nf < 8; ++nf) {
        f16x8 bf = *(const f16x8*)&W1g[(nf * 16 + l16) * 32 + quad * 8];
        acc[0][nf] = __builtin_amdgcn_mfma_f32_16x16x32_f16(a0, bf, acc[0][nf], 0, 0, 0);
        acc[1][nf] = __builtin_amdgcn_mfma_f32_16x16x32_f16(a1, bf, acc[1][nf], 0, 0, 0);
    }
#pragma unroll
    for (int mf = 0; mf < 2; ++mf) {
        const size_t rowb = ((size_t)b * 256 + i0 + 2 * w + mf) * 256 + j0;
#pragma unroll
        for (int nf = 0; nf < 8; ++nf) {
            const float bv = bias[nf * 16 + l16];
#pragma unroll
            for (int r = 0; r < 4; ++r)
                outp[(rowb + quad * 4 + r) * 128 + nf * 16 + l16] =
                    (_Float16)fmaxf(acc[mf][nf][r] + bv, 0.f);
        }
    }
}

// ---------------- middle layers: M=128 (8 rows x 16 px), N=128, K=640 -------
// 2x2 wave grid: wave(mg,ng) owns rows r0..r0+3 and oc n0..n0+63.
// Ring-3 B prefetch (2 iters ahead, ~160cy cover vs ~200cy L2 latency),
// ring-2 A prefetch (1 iter ahead, ~80cy cover vs ~120cy LDS latency).
template<int LAYER>
__global__ __launch_bounds__(256, 3) void gmid(
    const _Float16* __restrict__ in, const float* __restrict__ bias,
    _Float16* __restrict__ outp)
{
    const _Float16* wt = (LAYER == 2) ? W2g : W3g;
    __shared__ _Float16 Al[10 * 18 * 136];
    const int tid = threadIdx.x;
    const int j0 = blockIdx.x * 16, i0 = blockIdx.y * 8, b = blockIdx.z;

    for (int t = tid; t < 2880; t += 256) {     // 10 rows x 18 px x 16 chunks
        int r = t / 288, rem = t - r * 288, p = rem >> 4, q = rem & 15;
        int gi = i0 - 1 + r, gj = j0 - 1 + p;
        f16x8 v = {0, 0, 0, 0, 0, 0, 0, 0};
        if (((unsigned)gi < 256u) && ((unsigned)gj < 256u))
            v = *(const f16x8*)&in[(((size_t)b * 256 + gi) * 256 + gj) * 128 + q * 8];
        *(f16x8*)&Al[(r * 18 + p) * 136 + q * 8] = v;
    }
    __syncthreads();

    const int lane = tid & 63, w = tid >> 6;
    const int l16 = lane & 15, quad = lane >> 4;
    const int mg = w & 1, ng = w >> 1;
    const int r0 = mg * 4;                       // first of 4 rows
    const int n0 = ng * 64;                      // first of 64 oc

    const _Float16* wb = wt + (size_t)(n0 + l16) * 32 + quad * 8;
    // B frag (ks, nf) at wb + ks*4096 + nf*512

    f32x4 acc[4][4] = {};
    const int DR[5] = {1, 0, 2, 1, 1}, DP[5] = {1, 1, 1, 0, 2};

    f16x8 br[3][4], ar[2][4];
    // preload: B for ks=0,1 ; A for ks=0 (tap0: DR=1,DP=1, kc=0)
#pragma unroll
    for (int pk = 0; pk < 2; ++pk)
#pragma unroll
        for (int nf = 0; nf < 4; ++nf)
            br[pk][nf] = *(const f16x8*)(wb + (size_t)pk * 4096 + nf * 512);
#pragma unroll
    for (int r = 0; r < 4; ++r)
        ar[0][r] = *(const f16x8*)&Al[((1 + r0 + r) * 18 + 1 + l16) * 136 + quad * 8];

#pragma unroll
    for (int ks = 0; ks < 20; ++ks) {
        if (ks + 2 < 20) {                       // B two iterations ahead
#pragma unroll
            for (int nf = 0; nf < 4; ++nf)
                br[(ks + 2) % 3][nf] =
                    *(const f16x8*)(wb + (size_t)(ks + 2) * 4096 + nf * 512);
        }
        if (ks + 1 < 20) {                       // A one iteration ahead
            const int t2 = (ks + 1) >> 2, kc2 = (ks + 1) & 3;
            const int ko2 = kc2 * 32 + quad * 8;
#pragma unroll
            for (int r = 0; r < 4; ++r)
                ar[(ks + 1) & 1][r] =
                    *(const f16x8*)&Al[((DR[t2] + r0 + r) * 18 + DP[t2] + l16) * 136 + ko2];
        }
#pragma unroll
        for (int r = 0; r < 4; ++r)
#pragma unroll
            for (int nf = 0; nf < 4; ++nf)
                acc[r][nf] = __builtin_amdgcn_mfma_f32_16x16x32_f16(
                    ar[ks & 1][r], br[ks % 3][nf], acc[r][nf], 0, 0, 0);
    }

#pragma unroll
    for (int r = 0; r < 4; ++r) {
        const size_t rowb = ((size_t)b * 256 + i0 + r0 + r) * 256 + j0;
#pragma unroll
        for (int nf = 0; nf < 4; ++nf) {
            const float bv = bias[n0 + nf * 16 + l16];
#pragma unroll
            for (int vi = 0; vi < 4; ++vi)
                outp[(rowb + quad * 4 + vi) * 128 + n0 + nf * 16 + l16] =
                    (_Float16)fmaxf(acc[r][nf][vi] + bv, 0.f);
        }
    }
}

// ---------------- L4: 128 -> 6 (pad 16), MFMA, fp32 NCHW out ----------------
__global__ __launch_bounds__(256, 3) void g4(
    const _Float16* __restrict__ in, const float* __restrict__ bias,
    float* __restrict__ outp)
{
    __shared__ _Float16 Al[6 * 18 * 136];
    const int tid = threadIdx.x;
    const int jt = blockIdx.x, it = blockIdx.y, b = blockIdx.z;
    const int i0 = it * 4, j0 = jt * 16;

    for (int t = tid; t < 6 * 18 * 16; t += 256) {
        int r = t / 288, rem = t % 288, p = rem >> 4, q = rem & 15;
        int gi = i0 - 1 + r, gj = j0 - 1 + p;
        f16x8 v = {0, 0, 0, 0, 0, 0, 0, 0};
        if (((unsigned)gi < 256u) && ((unsigned)gj < 256u))
            v = *(const f16x8*)&in[(((size_t)b * 256 + gi) * 256 + gj) * 128 + q * 8];
        *(f16x8*)&Al[(r * 18 + p) * 136 + q * 8] = v;
    }
    __syncthreads();

    const int lane = tid & 63, wid = tid >> 6;
    const int l16 = lane & 15, quad = lane >> 4;
    f32x4 acc = {};
    const int DR[5] = {1, 0, 2, 1, 1}, DP[5] = {1, 1, 1, 0, 2};

#pragma unroll
    for (int ks = 0; ks < 20; ++ks) {
        const int tap = ks >> 2, kc = ks & 3;
        const int koff = kc * 32 + quad * 8;
        f16x8 bf = *(const f16x8*)&W4g[(size_t)(tap * 16 + l16) * 128 + koff];
        f16x8 af = *(const f16x8*)&Al[((DR[tap] + wid) * 18 + DP[tap] + l16) * 136 + koff];
        acc = __builtin_amdgcn_mfma_f32_16x16x32_f16(af, bf, acc, 0, 0, 0);
    }

    if (l16 < 6) {
        const float bb = bias[l16];
        const int i = i0 + wid;
#pragma unroll
        for (int vi = 0; vi < 4; ++vi) {
            int jj = j0 + quad * 4 + vi;
            outp[(((size_t)b * 6 + l16) << 16) + i * 256 + jj] = acc[vi] + bb;
        }
    }
}

extern "C" void kernel_launch(void* const* d_in, const int* in_sizes, int n_in,
                              void* d_out, int out_size, void* d_ws, size_t ws_size,
                              hipStream_t stream) {
    const float* x  = (const float*)d_in[0];
    const float* w1 = (const float*)d_in[1];
    const float* b1 = (const float*)d_in[2];
    const float* w2 = (const float*)d_in[3];
    const float* b2 = (const float*)d_in[4];
    const float* w3 = (const float*)d_in[5];
    const float* b3 = (const float*)d_in[6];
    const float* w4 = (const float*)d_in[7];
    const float* b4 = (const float*)d_in[8];
    float* out = (float*)d_out;

    const size_t act = (size_t)BB * HH * WW * 128;
    _Float16* A1 = (_Float16*)d_ws;
    _Float16* A2 = A1 + act;                    // exactly 268435456 B total

    prep<<<696, 256, 0, stream>>>(w1, w2, w3, w4);
    dim3 blk(256, 1, 1);
    dim3 gm(16, 32, 8);                         // 16-px x 8-row tiles
    g1<<<gm, blk, 0, stream>>>(x, b1, A1);
    gmid<2><<<gm, blk, 0, stream>>>(A1, b2, A2);
    gmid<3><<<gm, blk, 0, stream>>>(A2, b3, A1);
    g4<<<dim3(16, 64, 8), blk, 0, stream>>>(A1, b4, out);
}

// Round 4
// 419.015 us; speedup vs baseline: 1.7488x; 1.4474x over previous
//
#include <hip/hip_runtime.h>

// 4-layer 5-point cross-stencil CNN, implicit GEMM on MFMA (MI355X gfx950).
// Round 9: fix round-8 correctness bug (halo fixup coverage), same levers.
//   Round-8 post-mortem: fixup indexing (gidx=tid>>3, 0..31) was copied from
//   the 512-thread round-6 kernel; at 256 threads the left/right halo columns
//   and 4 bottom sites were never zeroed -> absmax 0.56 at image borders.
//   Fix: 2-pass fixup (gidx = (tid>>3)+32*pass covers 0..63 >= 56 groups).
//   Levers under test (round-8, unmeasured):
//   Lever 1: gmid staging via global_load_lds width=16 (45 wave-instrs/block,
//     no VGPR round-trip, no ds_writes, ~30 VALU/thread removed). LDS linear
//     180x128; chunk XOR swizzle (ch = c ^ (site&7)) applied on the global
//     SOURCE address (rule #21), reads XOR the same way -> uniform-8, free.
//   Lever 2: s_setprio(1/0) around the 16-MFMA block (independent staggered
//     blocks per CU = the regime where setprio measured +4-7%).
// MFMA 16x16x32_f16 layouts (verified round 3):
//   A[m=lane&15][k=quad*8+j], B[n=lane&15][k=quad*8+j], C: col=lane&15,
//   row=quad*4+reg.   Taps: 0=c,1=up,2=down,3=left,4=right.

#define BB   8
#define HH   256
#define WW   256

typedef _Float16 f16x8 __attribute__((ext_vector_type(8)));
typedef float    f32x4 __attribute__((ext_vector_type(4)));

// K-major fp16 weight tables (rewritten every launch by prep).
__device__ _Float16 W1g[128 * 32];       // [oc][k], k=tap*6+ic, 30..31 = 0
__device__ _Float16 W2g[20 * 128 * 32];  // [ks=tap*4+kc][oc][icb]
__device__ _Float16 W3g[20 * 128 * 32];
__device__ _Float16 W4g[5 * 16 * 128];   // [tap][oc(pad16)][ic]

__global__ void prep(const float* __restrict__ w1, const float* __restrict__ w2,
                     const float* __restrict__ w3, const float* __restrict__ w4)
{
    int idx = blockIdx.x * 256 + threadIdx.x;
    if (idx < 81920) {                                  // W2g
        int icb = idx & 31, oc = (idx >> 5) & 127, ks = idx >> 12;
        int tap = ks >> 2, ic = (ks & 3) * 32 + icb;
        W2g[idx] = (_Float16)w2[(oc * 128 + ic) * 5 + tap];
    } else if (idx < 163840) {                          // W3g
        int k = idx - 81920;
        int icb = k & 31, oc = (k >> 5) & 127, ks = k >> 12;
        int tap = ks >> 2, ic = (ks & 3) * 32 + icb;
        W3g[k] = (_Float16)w3[(oc * 128 + ic) * 5 + tap];
    } else if (idx < 174080) {                          // W4g
        int k = idx - 163840;
        int t = k / 2048, oc = (k >> 7) & 15, ic = k & 127;
        W4g[k] = (_Float16)((oc < 6) ? w4[(oc * 128 + ic) * 5 + t] : 0.f);
    } else if (idx < 178176) {                          // W1g
        int k = idx - 174080;
        int kk = k & 31, oc = k >> 5;
        float v = 0.f;
        if (kk < 30) {
            int tap = (kk * 43) >> 8;                   // kk/6 for kk<30
            int ic = kk - 6 * tap;
            v = w1[(oc * 6 + ic) * 5 + tap];
        }
        W1g[k] = (_Float16)v;
    }
}

// ---------------- L1: MFMA, K=32 (tap*6+ic, padded). NCHW fp32 -> NHWC fp16.
__global__ __launch_bounds__(256, 3) void g1(
    const float* __restrict__ x, const float* __restrict__ bias,
    _Float16* __restrict__ outp)
{
    __shared__ _Float16 Ap[128 * 40];
    const int tid = threadIdx.x;
    const int j0 = blockIdx.x * 16, i0 = blockIdx.y * 8, b = blockIdx.z;
    const int px = tid & 127, half = tid >> 7;
    const int pr = px >> 4, pp = px & 15;
#pragma unroll
    for (int it = 0; it < 16; ++it) {
        int k = it * 2 + half;
        float v = 0.f;
        if (k < 30) {
            int tap = (k * 43) >> 8, ic = k - 6 * tap;
            int di = (tap == 1) ? -1 : ((tap == 2) ? 1 : 0);
            int dj = (tap == 3) ? -1 : ((tap == 4) ? 1 : 0);
            int gi = i0 + pr + di, gj = j0 + pp + dj;
            if (((unsigned)gi < 256u) && ((unsigned)gj < 256u))
                v = x[(((size_t)b * 6 + ic) * 256 + gi) * 256 + gj];
        }
        Ap[px * 40 + k] = (_Float16)v;
    }
    __syncthreads();

    const int lane = tid & 63, w = tid >> 6, l16 = lane & 15, quad = lane >> 4;
    f32x4 acc[2][8] = {};
    f16x8 a0 = *(const f16x8*)&Ap[((2 * w + 0) * 16 + l16) * 40 + quad * 8];
    f16x8 a1 = *(const f16x8*)&Ap[((2 * w + 1) * 16 + l16) * 40 + quad * 8];
#pragma unroll
    for (int nf = 0; nf < 8; ++nf) {
        f16x8 bf = *(const f16x8*)&W1g[(nf * 16 + l16) * 32 + quad * 8];
        acc[0][nf] = __builtin_amdgcn_mfma_f32_16x16x32_f16(a0, bf, acc[0][nf], 0, 0, 0);
        acc[1][nf] = __builtin_amdgcn_mfma_f32_16x16x32_f16(a1, bf, acc[1][nf], 0, 0, 0);
    }
#pragma unroll
    for (int mf = 0; mf < 2; ++mf) {
        const size_t rowb = ((size_t)b * 256 + i0 + 2 * w + mf) * 256 + j0;
#pragma unroll
        for (int nf = 0; nf < 8; ++nf) {
            const float bv = bias[nf * 16 + l16];
#pragma unroll
            for (int r = 0; r < 4; ++r)
                outp[(rowb + quad * 4 + r) * 128 + nf * 16 + l16] =
                    (_Float16)fmaxf(acc[mf][nf][r] + bv, 0.f);
        }
    }
}

// ---------------- middle layers: M=128 (8 rows x 16 px), N=128, K=640 -------
// 2x2 wave grid: wave(mg,ng) owns rows r0..r0+3 and oc n0..n0+63.
// Staging: 45 global_load_lds(16B) wave-instrs into linear LDS [180][128],
// chunk XOR-swizzled via source address. 1-deep A/B prefetch (round-5 form).
template<int LAYER>
__global__ __launch_bounds__(256, 3) void gmid(
    const _Float16* __restrict__ in, const float* __restrict__ bias,
    _Float16* __restrict__ outp)
{
    const _Float16* wt = (LAYER == 2) ? W2g : W3g;
    __shared__ __align__(16) _Float16 Al[180 * 128];    // 46080 B, linear
    const int tid = threadIdx.x;
    const int lane = tid & 63, w = tid >> 6;
    const int j0 = blockIdx.x * 16, i0 = blockIdx.y * 8, b = blockIdx.z;
    const bool top = (blockIdx.y == 0), bot = (blockIdx.y == 31);
    const bool left = (blockIdx.x == 0), right = (blockIdx.x == 15);

    // ---- staging: instr m stages sites 4m..4m+3 (1024 B linear LDS).
    // lane l -> site s=4m+(l>>4); stored chunk (l&15) := global chunk
    // (l&15)^(s&7)  (XOR swizzle folded into the per-lane source address).
    {
        const int pxl = lane & 15;
#pragma unroll
        for (int k = 0; k < 12; ++k) {
            const int m = w + 4 * k;
            if (m < 45) {
                const int s = 4 * m + (lane >> 4);
                const int r = (s * 114) >> 11;          // s/18 for s<288
                const int p = s - 18 * r;
                int gi = i0 - 1 + r; gi = gi < 0 ? 0 : (gi > 255 ? 255 : gi);
                int gj = j0 - 1 + p; gj = gj < 0 ? 0 : (gj > 255 ? 255 : gj);
                const _Float16* src = in + (((size_t)(b * 256 + gi)) * 256 + gj) * 128
                                         + ((pxl ^ (s & 7)) << 3);
                __builtin_amdgcn_global_load_lds(
                    (const __attribute__((address_space(1))) void*)src,
                    (__attribute__((address_space(3))) void*)(Al + m * 512),
                    16, 0, 0);
            }
        }
    }
    __syncthreads();
    if (top | bot | left | right) {                     // zero clamp-loaded halo
        // 56 site-groups x 8 chunks = 448 slots; 256 threads x 2 passes.
#pragma unroll
        for (int pass = 0; pass < 2; ++pass) {
            const int gidx = (tid >> 3) + 32 * pass, c = tid & 7;
            int sid = -1;
            if (gidx < 18)      { if (top)   sid = gidx; }             // r=0
            else if (gidx < 36) { if (bot)   sid = 162 + gidx - 18; }  // r=9
            else if (gidx < 46) { if (left)  sid = (gidx - 36) * 18; }        // p=0
            else if (gidx < 56) { if (right) sid = (gidx - 46) * 18 + 17; }   // p=17
            if (sid >= 0) {
                const f16x8 z = {};
                *(f16x8*)(Al + sid * 128 + c * 16)     = z;
                *(f16x8*)(Al + sid * 128 + c * 16 + 8) = z;
            }
        }
        __syncthreads();
    }

    const int l16 = lane & 15, quad = lane >> 4;
    const int mg = w & 1, ng = w >> 1;
    const int r0 = mg * 4;                       // first of 4 rows
    const int n0 = ng * 64;                      // first of 64 oc

    const _Float16* wb = wt + (size_t)(n0 + l16) * 32 + quad * 8;
    // B frag (ks, nf) at wb + ks*4096 + nf*512

    f32x4 acc[4][4] = {};
    const int DR[5] = {1, 0, 2, 1, 1}, DP[5] = {1, 1, 1, 0, 2};

    // A-frag read: site s, chunk c = kc*4+quad, stored at c^(s&7)
    auto lda = [&](int ks, int r) -> f16x8 {
        const int tap = ks >> 2, kc = ks & 3;
        const int s = (DR[tap] + r0 + r) * 18 + DP[tap] + l16;
        const int ch = (kc * 4 + quad) ^ (s & 7);
        return *(const f16x8*)&Al[s * 128 + ch * 8];
    };

    f16x8 bc[4], bn[4], ac[4], an[4];
#pragma unroll
    for (int nf = 0; nf < 4; ++nf) bc[nf] = *(const f16x8*)(wb + nf * 512);
#pragma unroll
    for (int r = 0; r < 4; ++r) ac[r] = lda(0, r);

#pragma unroll
    for (int ks = 0; ks < 20; ++ks) {
        if (ks < 19) {
#pragma unroll
            for (int nf = 0; nf < 4; ++nf)
                bn[nf] = *(const f16x8*)(wb + (size_t)(ks + 1) * 4096 + nf * 512);
#pragma unroll
            for (int r = 0; r < 4; ++r) an[r] = lda(ks + 1, r);
        }
        __builtin_amdgcn_s_setprio(1);
#pragma unroll
        for (int r = 0; r < 4; ++r)
#pragma unroll
            for (int nf = 0; nf < 4; ++nf)
                acc[r][nf] = __builtin_amdgcn_mfma_f32_16x16x32_f16(
                    ac[r], bc[nf], acc[r][nf], 0, 0, 0);
        __builtin_amdgcn_s_setprio(0);
#pragma unroll
        for (int nf = 0; nf < 4; ++nf) bc[nf] = bn[nf];
#pragma unroll
        for (int r = 0; r < 4; ++r) ac[r] = an[r];
    }

#pragma unroll
    for (int r = 0; r < 4; ++r) {
        const size_t rowb = ((size_t)b * 256 + i0 + r0 + r) * 256 + j0;
#pragma unroll
        for (int nf = 0; nf < 4; ++nf) {
            const float bv = bias[n0 + nf * 16 + l16];
#pragma unroll
            for (int vi = 0; vi < 4; ++vi)
                outp[(rowb + quad * 4 + vi) * 128 + n0 + nf * 16 + l16] =
                    (_Float16)fmaxf(acc[r][nf][vi] + bv, 0.f);
        }
    }
}

// ---------------- L4: 128 -> 6 (pad 16), MFMA, fp32 NCHW out ----------------
__global__ __launch_bounds__(256, 3) void g4(
    const _Float16* __restrict__ in, const float* __restrict__ bias,
    float* __restrict__ outp)
{
    __shared__ _Float16 Al[6 * 18 * 136];
    const int tid = threadIdx.x;
    const int jt = blockIdx.x, it = blockIdx.y, b = blockIdx.z;
    const int i0 = it * 4, j0 = jt * 16;

    for (int t = tid; t < 6 * 18 * 16; t += 256) {
        int r = t / 288, rem = t % 288, p = rem >> 4, q = rem & 15;
        int gi = i0 - 1 + r, gj = j0 - 1 + p;
        f16x8 v = {0, 0, 0, 0, 0, 0, 0, 0};
        if (((unsigned)gi < 256u) && ((unsigned)gj < 256u))
            v = *(const f16x8*)&in[(((size_t)b * 256 + gi) * 256 + gj) * 128 + q * 8];
        *(f16x8*)&Al[(r * 18 + p) * 136 + q * 8] = v;
    }
    __syncthreads();

    const int lane = tid & 63, wid = tid >> 6;
    const int l16 = lane & 15, quad = lane >> 4;
    f32x4 acc = {};
    const int DR[5] = {1, 0, 2, 1, 1}, DP[5] = {1, 1, 1, 0, 2};

#pragma unroll
    for (int ks = 0; ks < 20; ++ks) {
        const int tap = ks >> 2, kc = ks & 3;
        const int koff = kc * 32 + quad * 8;
        f16x8 bf = *(const f16x8*)&W4g[(size_t)(tap * 16 + l16) * 128 + koff];
        f16x8 af = *(const f16x8*)&Al[((DR[tap] + wid) * 18 + DP[tap] + l16) * 136 + koff];
        acc = __builtin_amdgcn_mfma_f32_16x16x32_f16(af, bf, acc, 0, 0, 0);
    }

    if (l16 < 6) {
        const float bb = bias[l16];
        const int i = i0 + wid;
#pragma unroll
        for (int vi = 0; vi < 4; ++vi) {
            int jj = j0 + quad * 4 + vi;
            outp[(((size_t)b * 6 + l16) << 16) + i * 256 + jj] = acc[vi] + bb;
        }
    }
}

extern "C" void kernel_launch(void* const* d_in, const int* in_sizes, int n_in,
                              void* d_out, int out_size, void* d_ws, size_t ws_size,
                              hipStream_t stream) {
    const float* x  = (const float*)d_in[0];
    const float* w1 = (const float*)d_in[1];
    const float* b1 = (const float*)d_in[2];
    const float* w2 = (const float*)d_in[3];
    const float* b2 = (const float*)d_in[4];
    const float* w3 = (const float*)d_in[5];
    const float* b3 = (const float*)d_in[6];
    const float* w4 = (const float*)d_in[7];
    const float* b4 = (const float*)d_in[8];
    float* out = (float*)d_out;

    const size_t act = (size_t)BB * HH * WW * 128;
    _Float16* A1 = (_Float16*)d_ws;
    _Float16* A2 = A1 + act;                    // exactly 268435456 B total

    prep<<<696, 256, 0, stream>>>(w1, w2, w3, w4);
    dim3 blk(256, 1, 1);
    dim3 gm(16, 32, 8);                         // 16-px x 8-row tiles
    g1<<<gm, blk, 0, stream>>>(x, b1, A1);
    gmid<2><<<gm, blk, 0, stream>>>(A1, b2, A2);
    gmid<3><<<gm, blk, 0, stream>>>(A2, b3, A1);
    g4<<<dim3(16, 64, 8), blk, 0, stream>>>(A1, b4, out);
}

// Round 5
// 390.495 us; speedup vs baseline: 1.8765x; 1.0730x over previous
//
#include <hip/hip_runtime.h>

// 4-layer 5-point cross-stencil CNN, implicit GEMM on MFMA (MI355X gfx950).
// Round 10: port round-9 gmid levers to g4 (gmid/g1/prep byte-identical to
// round 9, which passed at 419us with gmid=128us).
//   Round-9 post-mortem: gload_lds staging + setprio took gmid 178->128us
//   (FETCH 101->75.6MB, WRITE 131MB = ideal). Remaining mass: g1+g4+prep
//   ~163us. g4 was the old structure: 8192 blocks, 6x18 halo (50% overhead)
//   staged via VGPR round-trip for 20 MFMA per block.
//   New g4: 8-row x 16-px tiles (grid 16x32x8, 4096 blocks), the SAME
//   45x global_load_lds linear-LDS staging + source XOR swizzle + 2-pass
//   halo fixup as gmid (proven at 256 thr). M=128 px (8 frags), N=16
//   (6 oc padded), K=640; wave w owns rows 2w,2w+1 -> 40 MFMA/wave.
// MFMA 16x16x32_f16 layouts (verified round 3):
//   A[m=lane&15][k=quad*8+j], B[n=lane&15][k=quad*8+j], C: col=lane&15,
//   row=quad*4+reg.   Taps: 0=c,1=up,2=down,3=left,4=right.

#define BB   8
#define HH   256
#define WW   256

typedef _Float16 f16x8 __attribute__((ext_vector_type(8)));
typedef float    f32x4 __attribute__((ext_vector_type(4)));

// K-major fp16 weight tables (rewritten every launch by prep).
__device__ _Float16 W1g[128 * 32];       // [oc][k], k=tap*6+ic, 30..31 = 0
__device__ _Float16 W2g[20 * 128 * 32];  // [ks=tap*4+kc][oc][icb]
__device__ _Float16 W3g[20 * 128 * 32];
__device__ _Float16 W4g[5 * 16 * 128];   // [tap][oc(pad16)][ic]

__global__ void prep(const float* __restrict__ w1, const float* __restrict__ w2,
                     const float* __restrict__ w3, const float* __restrict__ w4)
{
    int idx = blockIdx.x * 256 + threadIdx.x;
    if (idx < 81920) {                                  // W2g
        int icb = idx & 31, oc = (idx >> 5) & 127, ks = idx >> 12;
        int tap = ks >> 2, ic = (ks & 3) * 32 + icb;
        W2g[idx] = (_Float16)w2[(oc * 128 + ic) * 5 + tap];
    } else if (idx < 163840) {                          // W3g
        int k = idx - 81920;
        int icb = k & 31, oc = (k >> 5) & 127, ks = k >> 12;
        int tap = ks >> 2, ic = (ks & 3) * 32 + icb;
        W3g[k] = (_Float16)w3[(oc * 128 + ic) * 5 + tap];
    } else if (idx < 174080) {                          // W4g
        int k = idx - 163840;
        int t = k / 2048, oc = (k >> 7) & 15, ic = k & 127;
        W4g[k] = (_Float16)((oc < 6) ? w4[(oc * 128 + ic) * 5 + t] : 0.f);
    } else if (idx < 178176) {                          // W1g
        int k = idx - 174080;
        int kk = k & 31, oc = k >> 5;
        float v = 0.f;
        if (kk < 30) {
            int tap = (kk * 43) >> 8;                   // kk/6 for kk<30
            int ic = kk - 6 * tap;
            v = w1[(oc * 6 + ic) * 5 + tap];
        }
        W1g[k] = (_Float16)v;
    }
}

// ---------------- L1: MFMA, K=32 (tap*6+ic, padded). NCHW fp32 -> NHWC fp16.
__global__ __launch_bounds__(256, 3) void g1(
    const float* __restrict__ x, const float* __restrict__ bias,
    _Float16* __restrict__ outp)
{
    __shared__ _Float16 Ap[128 * 40];
    const int tid = threadIdx.x;
    const int j0 = blockIdx.x * 16, i0 = blockIdx.y * 8, b = blockIdx.z;
    const int px = tid & 127, half = tid >> 7;
    const int pr = px >> 4, pp = px & 15;
#pragma unroll
    for (int it = 0; it < 16; ++it) {
        int k = it * 2 + half;
        float v = 0.f;
        if (k < 30) {
            int tap = (k * 43) >> 8, ic = k - 6 * tap;
            int di = (tap == 1) ? -1 : ((tap == 2) ? 1 : 0);
            int dj = (tap == 3) ? -1 : ((tap == 4) ? 1 : 0);
            int gi = i0 + pr + di, gj = j0 + pp + dj;
            if (((unsigned)gi < 256u) && ((unsigned)gj < 256u))
                v = x[(((size_t)b * 6 + ic) * 256 + gi) * 256 + gj];
        }
        Ap[px * 40 + k] = (_Float16)v;
    }
    __syncthreads();

    const int lane = tid & 63, w = tid >> 6, l16 = lane & 15, quad = lane >> 4;
    f32x4 acc[2][8] = {};
    f16x8 a0 = *(const f16x8*)&Ap[((2 * w + 0) * 16 + l16) * 40 + quad * 8];
    f16x8 a1 = *(const f16x8*)&Ap[((2 * w + 1) * 16 + l16) * 40 + quad * 8];
#pragma unroll
    for (int nf = 0; nf < 8; ++nf) {
        f16x8 bf = *(const f16x8*)&W1g[(nf * 16 + l16) * 32 + quad * 8];
        acc[0][nf] = __builtin_amdgcn_mfma_f32_16x16x32_f16(a0, bf, acc[0][nf], 0, 0, 0);
        acc[1][nf] = __builtin_amdgcn_mfma_f32_16x16x32_f16(a1, bf, acc[1][nf], 0, 0, 0);
    }
#pragma unroll
    for (int mf = 0; mf < 2; ++mf) {
        const size_t rowb = ((size_t)b * 256 + i0 + 2 * w + mf) * 256 + j0;
#pragma unroll
        for (int nf = 0; nf < 8; ++nf) {
            const float bv = bias[nf * 16 + l16];
#pragma unroll
            for (int r = 0; r < 4; ++r)
                outp[(rowb + quad * 4 + r) * 128 + nf * 16 + l16] =
                    (_Float16)fmaxf(acc[mf][nf][r] + bv, 0.f);
        }
    }
}

// ---------------- middle layers: M=128 (8 rows x 16 px), N=128, K=640 -------
// 2x2 wave grid: wave(mg,ng) owns rows r0..r0+3 and oc n0..n0+63.
// Staging: 45 global_load_lds(16B) wave-instrs into linear LDS [180][128],
// chunk XOR-swizzled via source address. 1-deep A/B prefetch (round-5 form).
template<int LAYER>
__global__ __launch_bounds__(256, 3) void gmid(
    const _Float16* __restrict__ in, const float* __restrict__ bias,
    _Float16* __restrict__ outp)
{
    const _Float16* wt = (LAYER == 2) ? W2g : W3g;
    __shared__ __align__(16) _Float16 Al[180 * 128];    // 46080 B, linear
    const int tid = threadIdx.x;
    const int lane = tid & 63, w = tid >> 6;
    const int j0 = blockIdx.x * 16, i0 = blockIdx.y * 8, b = blockIdx.z;
    const bool top = (blockIdx.y == 0), bot = (blockIdx.y == 31);
    const bool left = (blockIdx.x == 0), right = (blockIdx.x == 15);

    // ---- staging: instr m stages sites 4m..4m+3 (1024 B linear LDS).
    // lane l -> site s=4m+(l>>4); stored chunk (l&15) := global chunk
    // (l&15)^(s&7)  (XOR swizzle folded into the per-lane source address).
    {
        const int pxl = lane & 15;
#pragma unroll
        for (int k = 0; k < 12; ++k) {
            const int m = w + 4 * k;
            if (m < 45) {
                const int s = 4 * m + (lane >> 4);
                const int r = (s * 114) >> 11;          // s/18 for s<288
                const int p = s - 18 * r;
                int gi = i0 - 1 + r; gi = gi < 0 ? 0 : (gi > 255 ? 255 : gi);
                int gj = j0 - 1 + p; gj = gj < 0 ? 0 : (gj > 255 ? 255 : gj);
                const _Float16* src = in + (((size_t)(b * 256 + gi)) * 256 + gj) * 128
                                         + ((pxl ^ (s & 7)) << 3);
                __builtin_amdgcn_global_load_lds(
                    (const __attribute__((address_space(1))) void*)src,
                    (__attribute__((address_space(3))) void*)(Al + m * 512),
                    16, 0, 0);
            }
        }
    }
    __syncthreads();
    if (top | bot | left | right) {                     // zero clamp-loaded halo
        // 56 site-groups x 8 chunks = 448 slots; 256 threads x 2 passes.
#pragma unroll
        for (int pass = 0; pass < 2; ++pass) {
            const int gidx = (tid >> 3) + 32 * pass, c = tid & 7;
            int sid = -1;
            if (gidx < 18)      { if (top)   sid = gidx; }             // r=0
            else if (gidx < 36) { if (bot)   sid = 162 + gidx - 18; }  // r=9
            else if (gidx < 46) { if (left)  sid = (gidx - 36) * 18; }        // p=0
            else if (gidx < 56) { if (right) sid = (gidx - 46) * 18 + 17; }   // p=17
            if (sid >= 0) {
                const f16x8 z = {};
                *(f16x8*)(Al + sid * 128 + c * 16)     = z;
                *(f16x8*)(Al + sid * 128 + c * 16 + 8) = z;
            }
        }
        __syncthreads();
    }

    const int l16 = lane & 15, quad = lane >> 4;
    const int mg = w & 1, ng = w >> 1;
    const int r0 = mg * 4;                       // first of 4 rows
    const int n0 = ng * 64;                      // first of 64 oc

    const _Float16* wb = wt + (size_t)(n0 + l16) * 32 + quad * 8;
    // B frag (ks, nf) at wb + ks*4096 + nf*512

    f32x4 acc[4][4] = {};
    const int DR[5] = {1, 0, 2, 1, 1}, DP[5] = {1, 1, 1, 0, 2};

    // A-frag read: site s, chunk c = kc*4+quad, stored at c^(s&7)
    auto lda = [&](int ks, int r) -> f16x8 {
        const int tap = ks >> 2, kc = ks & 3;
        const int s = (DR[tap] + r0 + r) * 18 + DP[tap] + l16;
        const int ch = (kc * 4 + quad) ^ (s & 7);
        return *(const f16x8*)&Al[s * 128 + ch * 8];
    };

    f16x8 bc[4], bn[4], ac[4], an[4];
#pragma unroll
    for (int nf = 0; nf < 4; ++nf) bc[nf] = *(const f16x8*)(wb + nf * 512);
#pragma unroll
    for (int r = 0; r < 4; ++r) ac[r] = lda(0, r);

#pragma unroll
    for (int ks = 0; ks < 20; ++ks) {
        if (ks < 19) {
#pragma unroll
            for (int nf = 0; nf < 4; ++nf)
                bn[nf] = *(const f16x8*)(wb + (size_t)(ks + 1) * 4096 + nf * 512);
#pragma unroll
            for (int r = 0; r < 4; ++r) an[r] = lda(ks + 1, r);
        }
        __builtin_amdgcn_s_setprio(1);
#pragma unroll
        for (int r = 0; r < 4; ++r)
#pragma unroll
            for (int nf = 0; nf < 4; ++nf)
                acc[r][nf] = __builtin_amdgcn_mfma_f32_16x16x32_f16(
                    ac[r], bc[nf], acc[r][nf], 0, 0, 0);
        __builtin_amdgcn_s_setprio(0);
#pragma unroll
        for (int nf = 0; nf < 4; ++nf) bc[nf] = bn[nf];
#pragma unroll
        for (int r = 0; r < 4; ++r) ac[r] = an[r];
    }

#pragma unroll
    for (int r = 0; r < 4; ++r) {
        const size_t rowb = ((size_t)b * 256 + i0 + r0 + r) * 256 + j0;
#pragma unroll
        for (int nf = 0; nf < 4; ++nf) {
            const float bv = bias[n0 + nf * 16 + l16];
#pragma unroll
            for (int vi = 0; vi < 4; ++vi)
                outp[(rowb + quad * 4 + vi) * 128 + n0 + nf * 16 + l16] =
                    (_Float16)fmaxf(acc[r][nf][vi] + bv, 0.f);
        }
    }
}

// ---------------- L4: 128 -> 6 (pad 16), gmid-style tiles + gload_lds -------
// 8-row x 16-px tile (grid 16x32x8). Staging/fixup identical to gmid.
// M = 128 px (8 frags of 16), N = 16 (6 oc + pad), K = 640.
// Wave w computes M-frags {2w, 2w+1} (rows 2w, 2w+1). 40 MFMA/wave.
__global__ __launch_bounds__(256, 3) void g4(
    const _Float16* __restrict__ in, const float* __restrict__ bias,
    float* __restrict__ outp)
{
    __shared__ __align__(16) _Float16 Al[180 * 128];    // 46080 B, linear
    const int tid = threadIdx.x;
    const int lane = tid & 63, w = tid >> 6;
    const int j0 = blockIdx.x * 16, i0 = blockIdx.y * 8, b = blockIdx.z;
    const bool top = (blockIdx.y == 0), bot = (blockIdx.y == 31);
    const bool left = (blockIdx.x == 0), right = (blockIdx.x == 15);

    {
        const int pxl = lane & 15;
#pragma unroll
        for (int k = 0; k < 12; ++k) {
            const int m = w + 4 * k;
            if (m < 45) {
                const int s = 4 * m + (lane >> 4);
                const int r = (s * 114) >> 11;          // s/18 for s<288
                const int p = s - 18 * r;
                int gi = i0 - 1 + r; gi = gi < 0 ? 0 : (gi > 255 ? 255 : gi);
                int gj = j0 - 1 + p; gj = gj < 0 ? 0 : (gj > 255 ? 255 : gj);
                const _Float16* src = in + (((size_t)(b * 256 + gi)) * 256 + gj) * 128
                                         + ((pxl ^ (s & 7)) << 3);
                __builtin_amdgcn_global_load_lds(
                    (const __attribute__((address_space(1))) void*)src,
                    (__attribute__((address_space(3))) void*)(Al + m * 512),
                    16, 0, 0);
            }
        }
    }
    __syncthreads();
    if (top | bot | left | right) {                     // zero clamp-loaded halo
#pragma unroll
        for (int pass = 0; pass < 2; ++pass) {
            const int gidx = (tid >> 3) + 32 * pass, c = tid & 7;
            int sid = -1;
            if (gidx < 18)      { if (top)   sid = gidx; }             // r=0
            else if (gidx < 36) { if (bot)   sid = 162 + gidx - 18; }  // r=9
            else if (gidx < 46) { if (left)  sid = (gidx - 36) * 18; }        // p=0
            else if (gidx < 56) { if (right) sid = (gidx - 46) * 18 + 17; }   // p=17
            if (sid >= 0) {
                const f16x8 z = {};
                *(f16x8*)(Al + sid * 128 + c * 16)     = z;
                *(f16x8*)(Al + sid * 128 + c * 16 + 8) = z;
            }
        }
        __syncthreads();
    }

    const int l16 = lane & 15, quad = lane >> 4;
    const int DR[5] = {1, 0, 2, 1, 1}, DP[5] = {1, 1, 1, 0, 2};

    // A-frag: row = output row within tile (0..7), m = px = l16.
    auto lda = [&](int ks, int row) -> f16x8 {
        const int tap = ks >> 2, kc = ks & 3;
        const int s = (DR[tap] + row) * 18 + DP[tap] + l16;
        const int ch = (kc * 4 + quad) ^ (s & 7);
        return *(const f16x8*)&Al[s * 128 + ch * 8];
    };

    f32x4 acc[2] = {};
#pragma unroll
    for (int ks = 0; ks < 20; ++ks) {
        const int tap = ks >> 2, kc = ks & 3;
        const int koff = kc * 32 + quad * 8;
        f16x8 bf = *(const f16x8*)&W4g[(size_t)(tap * 16 + l16) * 128 + koff];
        __builtin_amdgcn_s_setprio(1);
#pragma unroll
        for (int f = 0; f < 2; ++f)
            acc[f] = __builtin_amdgcn_mfma_f32_16x16x32_f16(
                lda(ks, 2 * w + f), bf, acc[f], 0, 0, 0);
        __builtin_amdgcn_s_setprio(0);
    }

    if (l16 < 6) {
        const float bb = bias[l16];
#pragma unroll
        for (int f = 0; f < 2; ++f) {
            const int i = i0 + 2 * w + f;
#pragma unroll
            for (int vi = 0; vi < 4; ++vi) {
                int jj = j0 + quad * 4 + vi;
                outp[(((size_t)b * 6 + l16) << 16) + i * 256 + jj] = acc[f][vi] + bb;
            }
        }
    }
}

extern "C" void kernel_launch(void* const* d_in, const int* in_sizes, int n_in,
                              void* d_out, int out_size, void* d_ws, size_t ws_size,
                              hipStream_t stream) {
    const float* x  = (const float*)d_in[0];
    const float* w1 = (const float*)d_in[1];
    const float* b1 = (const float*)d_in[2];
    const float* w2 = (const float*)d_in[3];
    const float* b2 = (const float*)d_in[4];
    const float* w3 = (const float*)d_in[5];
    const float* b3 = (const float*)d_in[6];
    const float* w4 = (const float*)d_in[7];
    const float* b4 = (const float*)d_in[8];
    float* out = (float*)d_out;

    const size_t act = (size_t)BB * HH * WW * 128;
    _Float16* A1 = (_Float16*)d_ws;
    _Float16* A2 = A1 + act;                    // exactly 268435456 B total

    prep<<<696, 256, 0, stream>>>(w1, w2, w3, w4);
    dim3 blk(256, 1, 1);
    dim3 gm(16, 32, 8);                         // 16-px x 8-row tiles
    g1<<<gm, blk, 0, stream>>>(x, b1, A1);
    gmid<2><<<gm, blk, 0, stream>>>(A1, b2, A2);
    gmid<3><<<gm, blk, 0, stream>>>(A2, b3, A1);
    g4<<<gm, blk, 0, stream>>>(A1, b4, out);
}

// Round 6
// 384.223 us; speedup vs baseline: 1.9072x; 1.0163x over previous
//
#include <hip/hip_runtime.h>

// 4-layer 5-point cross-stencil CNN, implicit GEMM on MFMA (MI355X gfx950).
// Round 11: thin the g1/g4 tail (~150us of 390). gmid/prep byte-identical to
// round 10 (417->390us; gmid=117us, FETCH 74MB, WRITE 131MB ideal).
//   g1: staging loop templated on <HALF, EDGE>: half=tid>>7 is wave-uniform,
//     so tap/ic/di/dj become compile-time and each plane's address folds to
//     xb + CONST. Interior blocks (82%) skip bounds checks (block-uniform).
//     ~280 -> ~80 VALU/thread; identical Ap layout, loads, MFMA, epilogue.
//   g4: 1-deep prefetch of (bf, af0, af1) in the k-loop (the one gmid lever
//     not yet ported; round-9-proven pattern). +12 VGPR, under the 3/SIMD cap.
// MFMA 16x16x32_f16 layouts (verified round 3):
//   A[m=lane&15][k=quad*8+j], B[n=lane&15][k=quad*8+j], C: col=lane&15,
//   row=quad*4+reg.   Taps: 0=c,1=up,2=down,3=left,4=right.

#define BB   8
#define HH   256
#define WW   256

typedef _Float16 f16x8 __attribute__((ext_vector_type(8)));
typedef float    f32x4 __attribute__((ext_vector_type(4)));

// K-major fp16 weight tables (rewritten every launch by prep).
__device__ _Float16 W1g[128 * 32];       // [oc][k], k=tap*6+ic, 30..31 = 0
__device__ _Float16 W2g[20 * 128 * 32];  // [ks=tap*4+kc][oc][icb]
__device__ _Float16 W3g[20 * 128 * 32];
__device__ _Float16 W4g[5 * 16 * 128];   // [tap][oc(pad16)][ic]

__global__ void prep(const float* __restrict__ w1, const float* __restrict__ w2,
                     const float* __restrict__ w3, const float* __restrict__ w4)
{
    int idx = blockIdx.x * 256 + threadIdx.x;
    if (idx < 81920) {                                  // W2g
        int icb = idx & 31, oc = (idx >> 5) & 127, ks = idx >> 12;
        int tap = ks >> 2, ic = (ks & 3) * 32 + icb;
        W2g[idx] = (_Float16)w2[(oc * 128 + ic) * 5 + tap];
    } else if (idx < 163840) {                          // W3g
        int k = idx - 81920;
        int icb = k & 31, oc = (k >> 5) & 127, ks = k >> 12;
        int tap = ks >> 2, ic = (ks & 3) * 32 + icb;
        W3g[k] = (_Float16)w3[(oc * 128 + ic) * 5 + tap];
    } else if (idx < 174080) {                          // W4g
        int k = idx - 163840;
        int t = k / 2048, oc = (k >> 7) & 15, ic = k & 127;
        W4g[k] = (_Float16)((oc < 6) ? w4[(oc * 128 + ic) * 5 + t] : 0.f);
    } else if (idx < 178176) {                          // W1g
        int k = idx - 174080;
        int kk = k & 31, oc = k >> 5;
        float v = 0.f;
        if (kk < 30) {
            int tap = (kk * 43) >> 8;                   // kk/6 for kk<30
            int ic = kk - 6 * tap;
            v = w1[(oc * 6 + ic) * 5 + tap];
        }
        W1g[k] = (_Float16)v;
    }
}

// ---------------- L1: MFMA, K=32 (tap*6+ic, padded). NCHW fp32 -> NHWC fp16.
// Staging planes k=2*it+HALF: HALF wave-uniform -> tap/ic/di/dj compile-time.
template<int HALF, bool EDGE>
__device__ __forceinline__ void g1_stage(const float* __restrict__ xb,
                                         _Float16* __restrict__ Ap,
                                         int px, int gi0, int gj0)
{
#pragma unroll
    for (int it = 0; it < 15; ++it) {
        const int k = 2 * it + HALF;                    // compile-time
        const int tap = k / 6, ic = k - 6 * tap;
        const int DI = (tap == 1) ? -1 : ((tap == 2) ? 1 : 0);
        const int DJ = (tap == 3) ? -1 : ((tap == 4) ? 1 : 0);
        const float* sp = xb + ic * 65536 + DI * 256 + DJ;
        float v;
        if (EDGE) {
            const int gi = gi0 + DI, gj = gj0 + DJ;
            v = ((unsigned)gi < 256u && (unsigned)gj < 256u) ? *sp : 0.f;
        } else {
            v = *sp;
        }
        Ap[px * 40 + k] = (_Float16)v;
    }
    Ap[px * 40 + 30 + HALF] = (_Float16)0.f;            // K-pad 30/31
}

__global__ __launch_bounds__(256, 3) void g1(
    const float* __restrict__ x, const float* __restrict__ bias,
    _Float16* __restrict__ outp)
{
    __shared__ _Float16 Ap[128 * 40];
    const int tid = threadIdx.x;
    const int j0 = blockIdx.x * 16, i0 = blockIdx.y * 8, b = blockIdx.z;
    const int px = tid & 127, half = tid >> 7;
    const int pr = px >> 4, pp = px & 15;
    const bool edge = (blockIdx.y == 0) | (blockIdx.y == 31) |
                      (blockIdx.x == 0) | (blockIdx.x == 15);
    const int gi0 = i0 + pr, gj0 = j0 + pp;
    const float* xb = x + (size_t)b * 6 * 65536 + gi0 * 256 + gj0;

    if (edge) {
        if (half == 0) g1_stage<0, true >(xb, Ap, px, gi0, gj0);
        else           g1_stage<1, true >(xb, Ap, px, gi0, gj0);
    } else {
        if (half == 0) g1_stage<0, false>(xb, Ap, px, gi0, gj0);
        else           g1_stage<1, false>(xb, Ap, px, gi0, gj0);
    }
    __syncthreads();

    const int lane = tid & 63, w = tid >> 6, l16 = lane & 15, quad = lane >> 4;
    f32x4 acc[2][8] = {};
    f16x8 a0 = *(const f16x8*)&Ap[((2 * w + 0) * 16 + l16) * 40 + quad * 8];
    f16x8 a1 = *(const f16x8*)&Ap[((2 * w + 1) * 16 + l16) * 40 + quad * 8];
#pragma unroll
    for (int nf = 0; nf < 8; ++nf) {
        f16x8 bf = *(const f16x8*)&W1g[(nf * 16 + l16) * 32 + quad * 8];
        acc[0][nf] = __builtin_amdgcn_mfma_f32_16x16x32_f16(a0, bf, acc[0][nf], 0, 0, 0);
        acc[1][nf] = __builtin_amdgcn_mfma_f32_16x16x32_f16(a1, bf, acc[1][nf], 0, 0, 0);
    }
#pragma unroll
    for (int mf = 0; mf < 2; ++mf) {
        const size_t rowb = ((size_t)b * 256 + i0 + 2 * w + mf) * 256 + j0;
#pragma unroll
        for (int nf = 0; nf < 8; ++nf) {
            const float bv = bias[nf * 16 + l16];
#pragma unroll
            for (int r = 0; r < 4; ++r)
                outp[(rowb + quad * 4 + r) * 128 + nf * 16 + l16] =
                    (_Float16)fmaxf(acc[mf][nf][r] + bv, 0.f);
        }
    }
}

// ---------------- middle layers: M=128 (8 rows x 16 px), N=128, K=640 -------
// 2x2 wave grid: wave(mg,ng) owns rows r0..r0+3 and oc n0..n0+63.
// Staging: 45 global_load_lds(16B) wave-instrs into linear LDS [180][128],
// chunk XOR-swizzled via source address. 1-deep A/B prefetch (round-5 form).
template<int LAYER>
__global__ __launch_bounds__(256, 3) void gmid(
    const _Float16* __restrict__ in, const float* __restrict__ bias,
    _Float16* __restrict__ outp)
{
    const _Float16* wt = (LAYER == 2) ? W2g : W3g;
    __shared__ __align__(16) _Float16 Al[180 * 128];    // 46080 B, linear
    const int tid = threadIdx.x;
    const int lane = tid & 63, w = tid >> 6;
    const int j0 = blockIdx.x * 16, i0 = blockIdx.y * 8, b = blockIdx.z;
    const bool top = (blockIdx.y == 0), bot = (blockIdx.y == 31);
    const bool left = (blockIdx.x == 0), right = (blockIdx.x == 15);

    // ---- staging: instr m stages sites 4m..4m+3 (1024 B linear LDS).
    // lane l -> site s=4m+(l>>4); stored chunk (l&15) := global chunk
    // (l&15)^(s&7)  (XOR swizzle folded into the per-lane source address).
    {
        const int pxl = lane & 15;
#pragma unroll
        for (int k = 0; k < 12; ++k) {
            const int m = w + 4 * k;
            if (m < 45) {
                const int s = 4 * m + (lane >> 4);
                const int r = (s * 114) >> 11;          // s/18 for s<288
                const int p = s - 18 * r;
                int gi = i0 - 1 + r; gi = gi < 0 ? 0 : (gi > 255 ? 255 : gi);
                int gj = j0 - 1 + p; gj = gj < 0 ? 0 : (gj > 255 ? 255 : gj);
                const _Float16* src = in + (((size_t)(b * 256 + gi)) * 256 + gj) * 128
                                         + ((pxl ^ (s & 7)) << 3);
                __builtin_amdgcn_global_load_lds(
                    (const __attribute__((address_space(1))) void*)src,
                    (__attribute__((address_space(3))) void*)(Al + m * 512),
                    16, 0, 0);
            }
        }
    }
    __syncthreads();
    if (top | bot | left | right) {                     // zero clamp-loaded halo
        // 56 site-groups x 8 chunks = 448 slots; 256 threads x 2 passes.
#pragma unroll
        for (int pass = 0; pass < 2; ++pass) {
            const int gidx = (tid >> 3) + 32 * pass, c = tid & 7;
            int sid = -1;
            if (gidx < 18)      { if (top)   sid = gidx; }             // r=0
            else if (gidx < 36) { if (bot)   sid = 162 + gidx - 18; }  // r=9
            else if (gidx < 46) { if (left)  sid = (gidx - 36) * 18; }        // p=0
            else if (gidx < 56) { if (right) sid = (gidx - 46) * 18 + 17; }   // p=17
            if (sid >= 0) {
                const f16x8 z = {};
                *(f16x8*)(Al + sid * 128 + c * 16)     = z;
                *(f16x8*)(Al + sid * 128 + c * 16 + 8) = z;
            }
        }
        __syncthreads();
    }

    const int l16 = lane & 15, quad = lane >> 4;
    const int mg = w & 1, ng = w >> 1;
    const int r0 = mg * 4;                       // first of 4 rows
    const int n0 = ng * 64;                      // first of 64 oc

    const _Float16* wb = wt + (size_t)(n0 + l16) * 32 + quad * 8;
    // B frag (ks, nf) at wb + ks*4096 + nf*512

    f32x4 acc[4][4] = {};
    const int DR[5] = {1, 0, 2, 1, 1}, DP[5] = {1, 1, 1, 0, 2};

    // A-frag read: site s, chunk c = kc*4+quad, stored at c^(s&7)
    auto lda = [&](int ks, int r) -> f16x8 {
        const int tap = ks >> 2, kc = ks & 3;
        const int s = (DR[tap] + r0 + r) * 18 + DP[tap] + l16;
        const int ch = (kc * 4 + quad) ^ (s & 7);
        return *(const f16x8*)&Al[s * 128 + ch * 8];
    };

    f16x8 bc[4], bn[4], ac[4], an[4];
#pragma unroll
    for (int nf = 0; nf < 4; ++nf) bc[nf] = *(const f16x8*)(wb + nf * 512);
#pragma unroll
    for (int r = 0; r < 4; ++r) ac[r] = lda(0, r);

#pragma unroll
    for (int ks = 0; ks < 20; ++ks) {
        if (ks < 19) {
#pragma unroll
            for (int nf = 0; nf < 4; ++nf)
                bn[nf] = *(const f16x8*)(wb + (size_t)(ks + 1) * 4096 + nf * 512);
#pragma unroll
            for (int r = 0; r < 4; ++r) an[r] = lda(ks + 1, r);
        }
        __builtin_amdgcn_s_setprio(1);
#pragma unroll
        for (int r = 0; r < 4; ++r)
#pragma unroll
            for (int nf = 0; nf < 4; ++nf)
                acc[r][nf] = __builtin_amdgcn_mfma_f32_16x16x32_f16(
                    ac[r], bc[nf], acc[r][nf], 0, 0, 0);
        __builtin_amdgcn_s_setprio(0);
#pragma unroll
        for (int nf = 0; nf < 4; ++nf) bc[nf] = bn[nf];
#pragma unroll
        for (int r = 0; r < 4; ++r) ac[r] = an[r];
    }

#pragma unroll
    for (int r = 0; r < 4; ++r) {
        const size_t rowb = ((size_t)b * 256 + i0 + r0 + r) * 256 + j0;
#pragma unroll
        for (int nf = 0; nf < 4; ++nf) {
            const float bv = bias[n0 + nf * 16 + l16];
#pragma unroll
            for (int vi = 0; vi < 4; ++vi)
                outp[(rowb + quad * 4 + vi) * 128 + n0 + nf * 16 + l16] =
                    (_Float16)fmaxf(acc[r][nf][vi] + bv, 0.f);
        }
    }
}

// ---------------- L4: 128 -> 6 (pad 16), gmid-style tiles + gload_lds -------
// 8-row x 16-px tile (grid 16x32x8). Staging/fixup identical to gmid.
// M = 128 px (8 frags of 16), N = 16 (6 oc + pad), K = 640.
// Wave w computes M-frags {2w, 2w+1} (rows 2w, 2w+1). 40 MFMA/wave.
// Round 11: 1-deep prefetch of (bf, af0, af1) across the k-loop.
__global__ __launch_bounds__(256, 3) void g4(
    const _Float16* __restrict__ in, const float* __restrict__ bias,
    float* __restrict__ outp)
{
    __shared__ __align__(16) _Float16 Al[180 * 128];    // 46080 B, linear
    const int tid = threadIdx.x;
    const int lane = tid & 63, w = tid >> 6;
    const int j0 = blockIdx.x * 16, i0 = blockIdx.y * 8, b = blockIdx.z;
    const bool top = (blockIdx.y == 0), bot = (blockIdx.y == 31);
    const bool left = (blockIdx.x == 0), right = (blockIdx.x == 15);

    {
        const int pxl = lane & 15;
#pragma unroll
        for (int k = 0; k < 12; ++k) {
            const int m = w + 4 * k;
            if (m < 45) {
                const int s = 4 * m + (lane >> 4);
                const int r = (s * 114) >> 11;          // s/18 for s<288
                const int p = s - 18 * r;
                int gi = i0 - 1 + r; gi = gi < 0 ? 0 : (gi > 255 ? 255 : gi);
                int gj = j0 - 1 + p; gj = gj < 0 ? 0 : (gj > 255 ? 255 : gj);
                const _Float16* src = in + (((size_t)(b * 256 + gi)) * 256 + gj) * 128
                                         + ((pxl ^ (s & 7)) << 3);
                __builtin_amdgcn_global_load_lds(
                    (const __attribute__((address_space(1))) void*)src,
                    (__attribute__((address_space(3))) void*)(Al + m * 512),
                    16, 0, 0);
            }
        }
    }
    __syncthreads();
    if (top | bot | left | right) {                     // zero clamp-loaded halo
#pragma unroll
        for (int pass = 0; pass < 2; ++pass) {
            const int gidx = (tid >> 3) + 32 * pass, c = tid & 7;
            int sid = -1;
            if (gidx < 18)      { if (top)   sid = gidx; }             // r=0
            else if (gidx < 36) { if (bot)   sid = 162 + gidx - 18; }  // r=9
            else if (gidx < 46) { if (left)  sid = (gidx - 36) * 18; }        // p=0
            else if (gidx < 56) { if (right) sid = (gidx - 46) * 18 + 17; }   // p=17
            if (sid >= 0) {
                const f16x8 z = {};
                *(f16x8*)(Al + sid * 128 + c * 16)     = z;
                *(f16x8*)(Al + sid * 128 + c * 16 + 8) = z;
            }
        }
        __syncthreads();
    }

    const int l16 = lane & 15, quad = lane >> 4;
    const int DR[5] = {1, 0, 2, 1, 1}, DP[5] = {1, 1, 1, 0, 2};

    // A-frag: row = output row within tile (0..7), m = px = l16.
    auto lda = [&](int ks, int row) -> f16x8 {
        const int tap = ks >> 2, kc = ks & 3;
        const int s = (DR[tap] + row) * 18 + DP[tap] + l16;
        const int ch = (kc * 4 + quad) ^ (s & 7);
        return *(const f16x8*)&Al[s * 128 + ch * 8];
    };
    auto ldb = [&](int ks) -> f16x8 {
        const int tap = ks >> 2, kc = ks & 3;
        return *(const f16x8*)&W4g[(size_t)(tap * 16 + l16) * 128 + kc * 32 + quad * 8];
    };

    f32x4 acc[2] = {};
    f16x8 bfc = ldb(0), bfn;
    f16x8 afc0 = lda(0, 2 * w), afc1 = lda(0, 2 * w + 1), afn0, afn1;
#pragma unroll
    for (int ks = 0; ks < 20; ++ks) {
        if (ks < 19) {
            bfn  = ldb(ks + 1);
            afn0 = lda(ks + 1, 2 * w);
            afn1 = lda(ks + 1, 2 * w + 1);
        }
        __builtin_amdgcn_s_setprio(1);
        acc[0] = __builtin_amdgcn_mfma_f32_16x16x32_f16(afc0, bfc, acc[0], 0, 0, 0);
        acc[1] = __builtin_amdgcn_mfma_f32_16x16x32_f16(afc1, bfc, acc[1], 0, 0, 0);
        __builtin_amdgcn_s_setprio(0);
        bfc = bfn; afc0 = afn0; afc1 = afn1;
    }

    if (l16 < 6) {
        const float bb = bias[l16];
#pragma unroll
        for (int f = 0; f < 2; ++f) {
            const int i = i0 + 2 * w + f;
#pragma unroll
            for (int vi = 0; vi < 4; ++vi) {
                int jj = j0 + quad * 4 + vi;
                outp[(((size_t)b * 6 + l16) << 16) + i * 256 + jj] = acc[f][vi] + bb;
            }
        }
    }
}

extern "C" void kernel_launch(void* const* d_in, const int* in_sizes, int n_in,
                              void* d_out, int out_size, void* d_ws, size_t ws_size,
                              hipStream_t stream) {
    const float* x  = (const float*)d_in[0];
    const float* w1 = (const float*)d_in[1];
    const float* b1 = (const float*)d_in[2];
    const float* w2 = (const float*)d_in[3];
    const float* b2 = (const float*)d_in[4];
    const float* w3 = (const float*)d_in[5];
    const float* b3 = (const float*)d_in[6];
    const float* w4 = (const float*)d_in[7];
    const float* b4 = (const float*)d_in[8];
    float* out = (float*)d_out;

    const size_t act = (size_t)BB * HH * WW * 128;
    _Float16* A1 = (_Float16*)d_ws;
    _Float16* A2 = A1 + act;                    // exactly 268435456 B total

    prep<<<696, 256, 0, stream>>>(w1, w2, w3, w4);
    dim3 blk(256, 1, 1);
    dim3 gm(16, 32, 8);                         // 16-px x 8-row tiles
    g1<<<gm, blk, 0, stream>>>(x, b1, A1);
    gmid<2><<<gm, blk, 0, stream>>>(A1, b2, A2);
    gmid<3><<<gm, blk, 0, stream>>>(A2, b3, A1);
    g4<<<gm, blk, 0, stream>>>(A1, b4, out);
}